// Round 1
// 664.524 us; speedup vs baseline: 1.0020x; 1.0020x over previous
//
#include <hip/hip_runtime.h>

#define NBINS 15

// DPP move helper: returns v permuted by CTRL; lanes not written by the pattern
// keep their own value (old = v, bound_ctrl = false).
template <int CTRL>
__device__ __forceinline__ float dpp_mov_f(float v) {
    return __int_as_float(__builtin_amdgcn_update_dpp(
        __float_as_int(v), __float_as_int(v), CTRL, 0xF, 0xF, false));
}

// 5-stage per-32-lane reductions, entirely on the VALU (no LDS pipe).
// After these, lanes 16-31 hold the half-A (lanes 0-31) result and
// lanes 48-63 hold the half-B (lanes 32-63) result.
//   0xB1  = quad_perm(1,0,3,2)  -> xor 1
//   0x4E  = quad_perm(2,3,0,1)  -> xor 2
//   0x141 = row_half_mirror     -> combine quads within 8
//   0x140 = row_mirror          -> combine 8-groups within 16
//   0x142 = row_bcast15         -> rows 1,3 pick up rows 0,2 totals
__device__ __forceinline__ float half_reduce_max(float v) {
    v = fmaxf(v, dpp_mov_f<0xB1>(v));
    v = fmaxf(v, dpp_mov_f<0x4E>(v));
    v = fmaxf(v, dpp_mov_f<0x141>(v));
    v = fmaxf(v, dpp_mov_f<0x140>(v));
    v = fmaxf(v, dpp_mov_f<0x142>(v));   // valid in rows 1,3 only (lanes 31/63 read)
    return v;
}
__device__ __forceinline__ float half_reduce_sum(float v) {
    v += dpp_mov_f<0xB1>(v);
    v += dpp_mov_f<0x4E>(v);
    v += dpp_mov_f<0x141>(v);
    v += dpp_mov_f<0x140>(v);
    v += dpp_mov_f<0x142>(v);            // valid in rows 1,3 only (lanes 31/63 read)
    return v;
}

// Pass 1: half-wave (32 lanes) per row, float4 per lane (32*16B = 512B = one row).
// All cross-lane reduction via DPP + readlane; argmax via ballot + dynamic readlane.
// Per-block 15-bin partials: count (u32), correct (u32), conf fixed-point *2^32 (u64).
__global__ __launch_bounds__(256, 8) void mce_pass1(
    const float* __restrict__ logits, const int* __restrict__ labels,
    unsigned long long* __restrict__ conf_part,
    unsigned int* __restrict__ cnt_part,
    unsigned int* __restrict__ acc_part,
    int n)
{
    __shared__ unsigned int s_cnt[NBINS];
    __shared__ unsigned int s_acc[NBINS];
    __shared__ unsigned long long s_conf[NBINS];
    if (threadIdx.x < NBINS) {
        s_cnt[threadIdx.x] = 0u;
        s_acc[threadIdx.x] = 0u;
        s_conf[threadIdx.x] = 0ULL;
    }
    __syncthreads();

    const int lane32 = threadIdx.x & 31;
    const int half   = (threadIdx.x >> 5) & 1;
    const int hw_global = blockIdx.x * 8 + (threadIdx.x >> 5);
    const int hw_total  = gridDim.x * 8;
    const int B = gridDim.x;

    for (int row = hw_global; row < n; row += hw_total) {
        const float4 v = *(const float4*)(logits + (size_t)row * 128 + lane32 * 4);
        const int lab = labels[row];                 // uniform per half, issued early

        // ---- max ----
        float m4 = fmaxf(fmaxf(v.x, v.y), fmaxf(v.z, v.w));
        float Mr = half_reduce_max(m4);
        const float MA = __int_as_float(__builtin_amdgcn_readlane(__float_as_int(Mr), 31));
        const float MB = __int_as_float(__builtin_amdgcn_readlane(__float_as_int(Mr), 63));
        const float Mh = half ? MB : MA;

        // ---- sum of exp(x - max) ----
        float e = __expf(v.x - Mh) + __expf(v.y - Mh) + __expf(v.z - Mh) + __expf(v.w - Mh);
        float Sr = half_reduce_sum(e);
        const int SA = __builtin_amdgcn_readlane(__float_as_int(Sr), 31);
        const int SB = __builtin_amdgcn_readlane(__float_as_int(Sr), 63);

        // ---- argmax, first occurrence (lane i covers contiguous idx 4i..4i+3) ----
        int idx_local = (v.x == Mh) ? 0 : (v.y == Mh) ? 1 : (v.z == Mh) ? 2 : 3;
        unsigned long long bal = __ballot(m4 == Mh);
        unsigned lo = (unsigned)bal;
        unsigned hi = (unsigned)(bal >> 32);
        int winA = __ffs(lo) - 1;                    // each half has >=1 match
        int winB = __ffs(hi) - 1;
        int predA = (winA << 2) + __builtin_amdgcn_readlane(idx_local, winA);
        int predB = (winB << 2) + __builtin_amdgcn_readlane(idx_local, winB + 32);

        if (lane32 == 0) {
            float Sh = __int_as_float(half ? SB : SA);
            int pred = half ? predB : predA;
            float conf = 1.0f / Sh;
            // searchsorted: bin = ceil(15*conf)-1, clamped
            int bin = (int)ceilf(conf * 15.0f) - 1;
            bin = max(0, min(NBINS - 1, bin));
            unsigned int acc = (pred == lab) ? 1u : 0u;
            // exact floor(conf * 2^32) via mantissa shift (== (u64)((double)conf*2^32))
            unsigned int cb = __float_as_uint(conf);
            unsigned int mant = (cb & 0x7fffffu) | 0x800000u;
            int sh = (int)(cb >> 23) - 118;          // exp-127 + 32 - 23
            unsigned long long fc = (sh >= 0)
                ? ((unsigned long long)mant << sh)
                : ((unsigned long long)mant >> (-sh));
            atomicAdd(&s_cnt[bin], 1u);
            atomicAdd(&s_acc[bin], acc);
            atomicAdd(&s_conf[bin], fc);
        }
    }
    __syncthreads();
    // transposed partials [bin][block] so pass2 reads are coalesced
    if (threadIdx.x < NBINS) {
        cnt_part[threadIdx.x * B + blockIdx.x]  = s_cnt[threadIdx.x];
        acc_part[threadIdx.x * B + blockIdx.x]  = s_acc[threadIdx.x];
        conf_part[(size_t)threadIdx.x * B + blockIdx.x] = s_conf[threadIdx.x];
    }
}

// Pass 2: one block, 15 waves; wave w reduces bin w across all B block-partials
// (now coalesced: consecutive lanes read consecutive blocks). Integer sums ->
// fully deterministic; then compute avgs/gap/mce and write 31 floats.
__global__ __launch_bounds__(960) void mce_pass2(
    const unsigned long long* __restrict__ conf_part,
    const unsigned int* __restrict__ cnt_part,
    const unsigned int* __restrict__ acc_part,
    int B, float* __restrict__ out)
{
    __shared__ float s_prob[NBINS], s_accu[NBINS], s_gap[NBINS];
    __shared__ int s_ne[NBINS];

    const int bin  = threadIdx.x >> 6;   // 0..14
    const int lane = threadIdx.x & 63;

    unsigned long long csum = 0ULL;
    unsigned int cn = 0u, ac = 0u;
    #pragma unroll 4
    for (int i = lane; i < B; i += 64) {
        csum += conf_part[(size_t)bin * B + i];
        cn   += cnt_part[bin * B + i];
        ac   += acc_part[bin * B + i];
    }
    #pragma unroll
    for (int off = 32; off >= 1; off >>= 1) {
        csum += __shfl_xor(csum, off, 64);
        cn   += __shfl_xor(cn, off, 64);
        ac   += __shfl_xor(ac, off, 64);
    }

    if (lane == 0) {
        if (cn > 0u) {
            float p = (float)(((double)csum * (1.0 / 4294967296.0)) / (double)cn);
            float a = (float)((double)ac / (double)cn);
            s_prob[bin] = p;
            s_accu[bin] = a;
            s_gap[bin]  = fabsf(p - a);
            s_ne[bin]   = 1;
        } else {
            s_prob[bin] = 0.0f;
            s_accu[bin] = 0.0f;
            s_gap[bin]  = 0.0f;
            s_ne[bin]   = 0;
        }
    }
    __syncthreads();

    if (threadIdx.x == 0) {
        float mce = -1e30f;
        for (int b = 0; b < NBINS; ++b)
            if (s_ne[b] && s_gap[b] > mce) mce = s_gap[b];
        out[0] = mce;
    }
    if (threadIdx.x < NBINS) {
        out[1 + threadIdx.x]  = s_prob[threadIdx.x];
        out[16 + threadIdx.x] = s_accu[threadIdx.x];
    }
}

extern "C" void kernel_launch(void* const* d_in, const int* in_sizes, int n_in,
                              void* d_out, int out_size, void* d_ws, size_t ws_size,
                              hipStream_t stream) {
    const float* logits = (const float*)d_in[0];
    const int*   labels = (const int*)d_in[1];
    const int n = in_sizes[1];              // 1e6 rows; C fixed at 128

    int B = 2048;                           // 2048 blocks * 4 waves = 8192 waves = 32/CU
    const size_t per_block = (size_t)NBINS * (8 + 4 + 4);
    if ((size_t)B * per_block > ws_size) B = (int)(ws_size / per_block);
    if (B < 1) B = 1;

    unsigned long long* conf_part = (unsigned long long*)d_ws;
    unsigned int* cnt_part = (unsigned int*)((char*)d_ws + (size_t)B * NBINS * 8);
    unsigned int* acc_part = (unsigned int*)((char*)d_ws + (size_t)B * NBINS * 12);

    mce_pass1<<<B, 256, 0, stream>>>(logits, labels, conf_part, cnt_part, acc_part, n);
    mce_pass2<<<1, 960, 0, stream>>>(conf_part, cnt_part, acc_part, B, (float*)d_out);
}